// Round 4
// baseline (162.989 us; speedup 1.0000x reference)
//
#include <hip/hip_runtime.h>

// Problem constants (setup_inputs: B=256, T=16, H=W=160, sms=2 -> t=16, h=w=80)
#define T_DIM 16
#define TSPLIT 2                 // t-halves per band (parallelism experiment)
#define T_HALF (T_DIM / TSPLIT)  // 8 slices per block
#define H2 80
#define W2 80
#define SLICE (H2 * W2)          // 6400 floats per t-slice
#define SAMPLE (T_DIM * SLICE)   // 102400 floats per sample
#define BANDS 5                  // row-bands per sample
#define ROWS_PER_BAND (H2 / BANDS)  // 16 rows
#define BLOCK (ROWS_PER_BAND * W2 / 4)  // 320 threads, one float4 each per slice
#define PARTS (BANDS * TSPLIT)   // partials per sample

__device__ __forceinline__ float4 relu4(float4 v) {
    v.x = fmaxf(v.x, 0.f); v.y = fmaxf(v.y, 0.f);
    v.z = fmaxf(v.z, 0.f); v.w = fmaxf(v.w, 0.f);
    return v;
}

// Phase 1: per-sample linear sums (S0, Sx, Sy, Sq) + TV sums (h, w, t).
// Grid = B * BANDS * TSPLIT. Each block: one 16-row band x 8 t-slices.
// Barrier-free; neighbors via overlapping global loads (L1/L2 hits).
// t-seam: upper-half blocks pre-load slice (t0-1)'s band for |s_t0 - s_{t0-1}|.
__global__ __launch_bounds__(BLOCK) void tsr_phase1(const float* __restrict__ scores,
                                                    float* __restrict__ ws) {
    __shared__ float red[(BLOCK / 64) * 7];

    const int blk  = blockIdx.x;
    const int b    = blk / PARTS;
    const int rem  = blk % PARTS;
    const int band = rem / TSPLIT;
    const int th   = rem % TSPLIT;
    const int t0   = th * T_HALF;
    const int tid  = threadIdx.x;

    const int y0  = band * ROWS_PER_BAND;
    const int r   = tid / (W2 / 4);   // local row 0..15
    const int cx  = tid % (W2 / 4);   // float4 index within row, 0..19
    const int y   = y0 + r;
    const int xb  = cx * 4;

    const float step = 2.0f / (float)(H2 - 1);   // h == w == 80 -> same step
    const float yy  = -1.0f + (float)y * step;
    const float xx0 = -1.0f + (float)(xb + 0) * step;
    const float xx1 = -1.0f + (float)(xb + 1) * step;
    const float xx2 = -1.0f + (float)(xb + 2) * step;
    const float xx3 = -1.0f + (float)(xb + 3) * step;
    const float yy2 = yy * yy;
    const float cq0 = xx0 * xx0 + yy2;
    const float cq1 = xx1 * xx1 + yy2;
    const float cq2 = xx2 * xx2 + yy2;
    const float cq3 = xx3 * xx3 + yy2;

    const float* sampBase = scores + (size_t)b * SAMPLE;
    const int rowOff = y * W2 + xb;                          // own float4 (floats)
    const int hOff = (y + 1 < H2) ? rowOff + W2 : rowOff;    // h-neighbor row (clamped)
    const int wOff = (xb + 4 < W2) ? rowOff + 4 : rowOff + 3;// w-boundary scalar (clamped)

    float s0 = 0.f, sx = 0.f, sy = 0.f, sq = 0.f;
    float tvh = 0.f, tvw = 0.f, tvt = 0.f;

    // Seam prologue: upper halves need the previous slice's value for the
    // t-diff at t = t0. Lower half (th==0) skips the t==0 diff entirely.
    float4 prev = make_float4(0.f, 0.f, 0.f, 0.f);
    if (th != 0) {
        prev = relu4(*(const float4*)(sampBase + (size_t)(t0 - 1) * SLICE + rowOff));
    }

#pragma unroll
    for (int i = 0; i < T_HALF; ++i) {
        const int t = t0 + i;
        const float* sl = sampBase + (size_t)t * SLICE;
        const float4 v4 = *(const float4*)(sl + rowOff);
        const float4 h4 = *(const float4*)(sl + hOff);
        const float  wn = sl[wOff];

        const float4 v = relu4(v4);
        const float4 hN = relu4(h4);
        const float  wN = fmaxf(wn, 0.f);

        // linear sums
        const float rs = v.x + v.y + v.z + v.w;
        s0 += rs;
        sy = fmaf(yy, rs, sy);
        sx = fmaf(xx0, v.x, sx); sx = fmaf(xx1, v.y, sx);
        sx = fmaf(xx2, v.z, sx); sx = fmaf(xx3, v.w, sx);
        sq = fmaf(cq0, v.x, sq); sq = fmaf(cq1, v.y, sq);
        sq = fmaf(cq2, v.z, sq); sq = fmaf(cq3, v.w, sq);

        // w-diffs: 3 internal + boundary (clamped -> 0 at row end)
        tvw += fabsf(v.y - v.x) + fabsf(v.z - v.y) + fabsf(v.w - v.z)
             + fabsf(wN - v.w);

        // h-diffs vs next row (clamped -> 0 at y==79)
        tvh += fabsf(hN.x - v.x) + fabsf(hN.y - v.y) +
               fabsf(hN.z - v.z) + fabsf(hN.w - v.w);

        // t-diffs: register-resident; skip only the global t==0 (th==0, i==0)
        if (th != 0 || i > 0) {
            tvt += fabsf(v.x - prev.x) + fabsf(v.y - prev.y) +
                   fabsf(v.z - prev.z) + fabsf(v.w - prev.w);
        }
        prev = v;
    }

    // block reduction: wave shuffle, then cross-wave via LDS
    float acc[7] = {s0, sx, sy, sq, tvh, tvw, tvt};
#pragma unroll
    for (int off = 32; off > 0; off >>= 1) {
#pragma unroll
        for (int i = 0; i < 7; ++i) acc[i] += __shfl_down(acc[i], off);
    }
    const int wave = tid >> 6;
    const int lane = tid & 63;
    if (lane == 0) {
#pragma unroll
        for (int i = 0; i < 7; ++i) red[wave * 7 + i] = acc[i];
    }
    __syncthreads();
    if (tid < 7) {
        float s = 0.f;
#pragma unroll
        for (int wv = 0; wv < BLOCK / 64; ++wv) s += red[wv * 7 + tid];
        ws[blk * 8 + tid] = s;  // distinct slot per block -> no init, no atomics
    }
}

// Phase 2: sum partials per sample, nonlinear combine, batch mean -> scalar
__global__ __launch_bounds__(256) void tsr_finalize(const float* __restrict__ ws,
                                                    float* __restrict__ out, int B) {
    __shared__ float red[256];
    const int tid = threadIdx.x;
    float acc = 0.f;
    const float ch = 1.0f / (float)(T_DIM * (H2 - 1) * W2);       // 1/101120
    const float cw = 1.0f / (float)(T_DIM * H2 * (W2 - 1));       // 1/101120
    const float ct = 0.3f / (float)((T_DIM - 1) * H2 * W2);       // 0.3/96000
    for (int b = tid; b < B; b += 256) {
        float p[7] = {0.f, 0.f, 0.f, 0.f, 0.f, 0.f, 0.f};
        for (int part = 0; part < PARTS; ++part) {
            const float* w = ws + (size_t)(b * PARTS + part) * 8;
#pragma unroll
            for (int i = 0; i < 7; ++i) p[i] += w[i];
        }
        const float S0 = p[0], Sx = p[1], Sy = p[2], Sq = p[3];
        const float Th = p[4], Tw = p[5], Tt = p[6];
        const float tot = fmaxf(S0, 1e-6f);
        const float inv = 1.0f / tot;
        const float mux = Sx * inv, muy = Sy * inv;
        const float m2 = mux * mux + muy * muy;
        const float compact = Sq * inv - 2.0f * m2 + m2 * (S0 * inv);
        const float tv = Th * ch + Tw * cw + Tt * ct;
        acc += compact + tv;
    }
    red[tid] = acc;
    __syncthreads();
    for (int s = 128; s > 0; s >>= 1) {
        if (tid < s) red[tid] += red[tid + s];
        __syncthreads();
    }
    if (tid == 0) out[0] = red[0] / (float)B;
}

extern "C" void kernel_launch(void* const* d_in, const int* in_sizes, int n_in,
                              void* d_out, int out_size, void* d_ws, size_t ws_size,
                              hipStream_t stream) {
    const float* scores = (const float*)d_in[0];
    const int B = in_sizes[0] / SAMPLE;  // 256
    float* ws = (float*)d_ws;

    tsr_phase1<<<B * PARTS, BLOCK, 0, stream>>>(scores, ws);
    tsr_finalize<<<1, 256, 0, stream>>>(ws, (float*)d_out, B);
}